// Round 3
// baseline (392.402 us; speedup 1.0000x reference)
//
#include <hip/hip_runtime.h>
#include <hip/hip_bf16.h>

#define TT 4096      // tokens (B*S)
#define DD 768       // model dim
#define FF 3072      // ffn dim
#define EE 8         // experts
#define NSLOT 8192   // 2*TT (top-2)
#define NSLOT_PAD 8320

// s_waitcnt imm encodings (gfx9): vmcnt[3:0]|expcnt<<4|lgkmcnt<<8|vmcnt[5:4]<<14
#define WVM4  0x0F74   // vmcnt(4),  lgkmcnt(15) -- steady-state: own step-k loads landed
#define WVM0  0x0F70   // vmcnt(0)               -- final drain

typedef __attribute__((ext_vector_type(8))) short bf16x8;
typedef __attribute__((ext_vector_type(4))) float f32x4;
typedef const __attribute__((address_space(1))) void* gas1_t;
typedef __attribute__((address_space(3))) void* las3_t;

// ---------------- router2: 256 blocks x 16 tokens; rw in LDS; no global atomics ----
__global__ __launch_bounds__(256) void router2_kernel(const float* __restrict__ x,
    const float* __restrict__ rw, int* __restrict__ tokE, float* __restrict__ tokW,
    int* __restrict__ blkCnt) {
  __shared__ float rws[EE * 832];
  __shared__ int cnt_s[EE];
  int tid = threadIdx.x;
  if (tid < EE) cnt_s[tid] = 0;
#pragma unroll
  for (int k = 0; k < 6; ++k) {
    int c = tid + k * 256;            // 0..1535
    int e = c / 192, rem = c % 192;
    int s = rem / 12, i = rem % 12;
    float4 v = *(const float4*)&rw[e * DD + s * 48 + i * 4];
    *(float4*)&rws[e * 832 + s * 52 + i * 4] = v;
  }
  __syncthreads();
  int lane = tid & 63;
  int sl = lane & 15;                  // d-slice
  int t = blockIdx.x * 16 + (tid >> 6) * 4 + (lane >> 4);
  const float4* xp = (const float4*)(x + (size_t)t * DD + sl * 48);
  float acc[EE];
#pragma unroll
  for (int e = 0; e < EE; ++e) acc[e] = 0.f;
#pragma unroll
  for (int i = 0; i < 12; ++i) {
    float4 xv = xp[i];
#pragma unroll
    for (int e = 0; e < EE; ++e) {
      float4 rv = *(const float4*)&rws[e * 832 + sl * 52 + i * 4];
      acc[e] = fmaf(xv.x, rv.x, fmaf(xv.y, rv.y, fmaf(xv.z, rv.z, fmaf(xv.w, rv.w, acc[e]))));
    }
  }
#pragma unroll
  for (int off = 8; off > 0; off >>= 1) {
#pragma unroll
    for (int e = 0; e < EE; ++e) acc[e] += __shfl_xor(acc[e], off);
  }
  if (sl == 0) {
    float v0 = -1e30f; int e0 = 0;
#pragma unroll
    for (int e = 0; e < EE; ++e) { if (acc[e] > v0) { v0 = acc[e]; e0 = e; } }
    float v1 = -1e30f; int e1 = 0;
#pragma unroll
    for (int e = 0; e < EE; ++e) { if (e != e0 && acc[e] > v1) { v1 = acc[e]; e1 = e; } }
    float w1 = 1.f / (1.f + __expf(v0 - v1));
    float w0 = 1.f - w1;
    tokE[2 * t] = e0; tokE[2 * t + 1] = e1;
    tokW[2 * t] = w0; tokW[2 * t + 1] = w1;
    atomicAdd(&cnt_s[e0], 1);
    atomicAdd(&cnt_s[e1], 1);
  }
  __syncthreads();
  if (tid < EE) blkCnt[blockIdx.x * EE + tid] = cnt_s[tid];
}

// ---------------- offsets2: 256-wide scan of blkCnt; offsets, bases, tile tables ---
__global__ __launch_bounds__(256) void offsets2_kernel(const int* __restrict__ blkCnt,
    int* __restrict__ offs, int* __restrict__ blkBase,
    int* __restrict__ tile1, int* __restrict__ tile2, int* __restrict__ meta) {
  __shared__ int wsum[4][EE];
  int tid = threadIdx.x;
  int lane = tid & 63, w = tid >> 6;
  int c[EE], s[EE];
#pragma unroll
  for (int e = 0; e < EE; ++e) { c[e] = blkCnt[tid * EE + e]; s[e] = c[e]; }
#pragma unroll
  for (int off = 1; off < 64; off <<= 1) {
#pragma unroll
    for (int e = 0; e < EE; ++e) {
      int v = __shfl_up(s[e], off);
      if (lane >= off) s[e] += v;
    }
  }
  if (lane == 63) {
#pragma unroll
    for (int e = 0; e < EE; ++e) wsum[w][e] = s[e];
  }
  __syncthreads();
#pragma unroll
  for (int e = 0; e < EE; ++e) {
    int pre = 0;
    for (int w2 = 0; w2 < w; ++w2) pre += wsum[w2][e];
    s[e] += pre;
  }
  int tot[EE];
#pragma unroll
  for (int e = 0; e < EE; ++e) tot[e] = wsum[0][e] + wsum[1][e] + wsum[2][e] + wsum[3][e];
  int offl[EE + 1];
  offl[0] = 0;
#pragma unroll
  for (int e = 0; e < EE; ++e) offl[e + 1] = offl[e] + tot[e];
#pragma unroll
  for (int e = 0; e < EE; ++e) blkBase[tid * EE + e] = offl[e] + s[e] - c[e];
  if (tid == 0) {
    for (int e = 0; e <= EE; ++e) offs[e] = offl[e];
    int n1 = 0, n2 = 0;
    for (int e = 0; e < EE; ++e) { n1 += (tot[e] + 127) / 128; n2 += (tot[e] + 63) / 64; }
    meta[0] = n1; meta[1] = n2;
  }
  if (tid < EE) {
    int p1 = 0, p2 = 0;
    for (int e = 0; e < tid; ++e) { p1 += (tot[e] + 127) / 128; p2 += (tot[e] + 63) / 64; }
    for (int m = 0; m < tot[tid]; m += 128) tile1[p1++] = (tid << 20) | m;
    for (int m = 0; m < tot[tid]; m += 64)  tile2[p2++] = (tid << 20) | m;
  }
}

// ---------------- scatter_gather2: coalesced copy to both slots; records slot->tok --
__global__ __launch_bounds__(256) void scatter_gather2_kernel(const float* __restrict__ x,
    const int* __restrict__ tokE, const float* __restrict__ tokW,
    const int* __restrict__ blkBase, int* __restrict__ slotIdx, float* __restrict__ slotW,
    int* __restrict__ slotTok, __hip_bfloat16* __restrict__ Xg) {
  __shared__ int base_s[EE], lcur[EE];
  __shared__ int sl_s[16][2];
  int tid = threadIdx.x;
  int b = blockIdx.x;
  if (tid < EE) { base_s[tid] = blkBase[b * EE + tid]; lcur[tid] = 0; }
  __syncthreads();
  if (tid < 16) {
    int t = b * 16 + tid;
    int e0 = tokE[2 * t], e1 = tokE[2 * t + 1];
    int s0 = base_s[e0] + atomicAdd(&lcur[e0], 1);
    int s1 = base_s[e1] + atomicAdd(&lcur[e1], 1);
    slotIdx[2 * t] = s0; slotIdx[2 * t + 1] = s1;
    slotW[s0] = tokW[2 * t]; slotW[s1] = tokW[2 * t + 1];
    slotTok[s0] = t; slotTok[s1] = t;
    sl_s[tid][0] = s0; sl_s[tid][1] = s1;
  }
  __syncthreads();
  int k = tid >> 4, p = tid & 15;
  int t = b * 16 + k;
  int s0 = sl_s[k][0], s1 = sl_s[k][1];
  const float4* src = (const float4*)(x + (size_t)t * DD);
  ushort4* d0 = (ushort4*)(Xg + (size_t)s0 * DD);
  ushort4* d1 = (ushort4*)(Xg + (size_t)s1 * DD);
#pragma unroll
  for (int i = 0; i < 12; ++i) {
    int idx = i * 16 + p;               // lanes contiguous -> coalesced 256B/128B
    float4 v = src[idx];
    union { ushort4 u; __hip_bfloat16 h[4]; } cv;
    cv.h[0] = __float2bfloat16(v.x);
    cv.h[1] = __float2bfloat16(v.y);
    cv.h[2] = __float2bfloat16(v.z);
    cv.h[3] = __float2bfloat16(v.w);
    d0[idx] = cv.u;
    d1[idx] = cv.u;
  }
}

// fused transpose-convert for both weight tensors: [K][N] fp32 -> [N][K] bf16
__global__ void transpose_convert_kernel(const float* __restrict__ w_fc, __hip_bfloat16* __restrict__ wfcT,
                                         const float* __restrict__ w_proj, __hip_bfloat16* __restrict__ wprojT) {
  __shared__ float tile[64][65];
  int bx = blockIdx.x;
  const float* S; __hip_bfloat16* D; int K, N, n0, k0;
  if (bx < 576) { S = w_fc;   D = wfcT;   K = DD; N = FF; n0 = (bx % 48) * 64; k0 = (bx / 48) * 64; }
  else { bx -= 576; S = w_proj; D = wprojT; K = FF; N = DD; n0 = (bx % 12) * 64; k0 = (bx / 12) * 64; }
  S += (size_t)blockIdx.z * K * N;
  D += (size_t)blockIdx.z * K * N;
  int tid = threadIdx.x;
#pragma unroll
  for (int i = 0; i < 4; ++i) {
    int slot = i * 256 + tid;
    int r = slot >> 4, c4 = slot & 15;
    float4 v = *(const float4*)&S[(size_t)(k0 + r) * N + n0 + c4 * 4];
    tile[r][c4 * 4 + 0] = v.x; tile[r][c4 * 4 + 1] = v.y;
    tile[r][c4 * 4 + 2] = v.z; tile[r][c4 * 4 + 3] = v.w;
  }
  __syncthreads();
#pragma unroll
  for (int i = 0; i < 4; ++i) {
    int slot = i * 256 + tid;
    int n = slot >> 4, kc = slot & 15;
    union { ushort4 u; __hip_bfloat16 h[4]; } cv;
    cv.h[0] = __float2bfloat16(tile[kc * 4 + 0][n]);
    cv.h[1] = __float2bfloat16(tile[kc * 4 + 1][n]);
    cv.h[2] = __float2bfloat16(tile[kc * 4 + 2][n]);
    cv.h[3] = __float2bfloat16(tile[kc * 4 + 3][n]);
    *(ushort4*)&D[(size_t)(n0 + n) * K + k0 + kc * 4] = cv.u;
  }
}

// fast exact-gelu via A&S 7.1.26 erf (max abs err 1.5e-7)
__device__ __forceinline__ float gelu_f(float v) {
  float z = v * 0.70710678118654752f;
  float az = fabsf(z);
  float t = 1.0f / (1.0f + 0.3275911f * az);
  float poly = t * (0.254829592f + t * (-0.284496736f + t * (1.421413741f +
               t * (-1.453152027f + t * 1.061405429f))));
  float erf_abs = 1.0f - poly * __expf(-az * az);
  float erf = copysignf(erf_abs, z);
  return 0.5f * v * (1.0f + erf);
}

// chunk swizzle for BK=32 rows (4 x 16B chunks/row)
__device__ __forceinline__ int swz4(int m) { return (m + (m >> 2)) & 3; }

// --- single-barrier pipelined K-step (3-stage LDS ring, depth-2 prefetch) ---
// Step k: wait vmcnt(4) [own step-k loads landed; k's loads were issued at k-2],
// barrier [all waves' step-k loads landed AND all waves done reading buf(k-1)],
// issue step k+2 into buf(k-1) [safe: barrier above], ds_read buf(k) + MFMA
// [compiler inserts fine-grained lgkmcnt before consuming MFMAs; by the time a
// wave reaches the NEXT barrier all its ds_reads have retired, so no trailing
// lgkmcnt(0)/second barrier is needed].
#define G_ISSUE(PRE) \
  __builtin_amdgcn_global_load_lds((gas1_t)gA0, (las3_t)(&As[PRE][0] + fs0 * 8), 16, 0, 0); \
  __builtin_amdgcn_global_load_lds((gas1_t)gA1, (las3_t)(&As[PRE][0] + fs1 * 8), 16, 0, 0); \
  __builtin_amdgcn_global_load_lds((gas1_t)gB0, (las3_t)(&Bs[PRE][0] + fs0 * 8), 16, 0, 0); \
  __builtin_amdgcn_global_load_lds((gas1_t)gB1, (las3_t)(&Bs[PRE][0] + fs1 * 8), 16, 0, 0); \
  gA0 += 32; gA1 += 32; gB0 += 32; gB1 += 32;

#define G_COMP(CUR) \
  { const short* curA = &As[CUR][0]; const short* curB = &Bs[CUR][0]; \
    bf16x8 af[4], bfr[4]; \
    _Pragma("unroll") for (int mi = 0; mi < 4; ++mi) af[mi] = *(const bf16x8*)(curA + aoff[mi]); \
    _Pragma("unroll") for (int ni = 0; ni < 4; ++ni) bfr[ni] = *(const bf16x8*)(curB + boff[ni]); \
    _Pragma("unroll") for (int mi = 0; mi < 4; ++mi) \
      _Pragma("unroll") for (int ni = 0; ni < 4; ++ni) \
        acc[mi][ni] = __builtin_amdgcn_mfma_f32_16x16x32_bf16(af[mi], bfr[ni], acc[mi][ni], 0, 0, 0); }

// steady step: CUR = k%3, PRE = (k-1)%3 (target of issue for step k+2)
#define S_MAIN(CUR, PRE) \
  __builtin_amdgcn_s_waitcnt(WVM4); \
  __builtin_amdgcn_s_barrier(); \
  G_ISSUE(PRE) \
  G_COMP(CUR)

#define S_TAIL(CUR, WAITIMM) \
  __builtin_amdgcn_s_waitcnt(WAITIMM); \
  __builtin_amdgcn_s_barrier(); \
  G_COMP(CUR)

// GEMM1: H = gelu(Xg @ wfcT + b_fc); 128x128 tile, BK=32, 3-stage ring, depth-2
// prefetch, ONE barrier per step; XCD-swizzled block mapping.
__global__ __launch_bounds__(256) void gemm1_kernel(const __hip_bfloat16* __restrict__ Xg,
    const __hip_bfloat16* __restrict__ wfcT, const float* __restrict__ b_fc,
    __hip_bfloat16* __restrict__ H, const int* __restrict__ offs,
    const int* __restrict__ tile1, const int* __restrict__ meta) {
  __shared__ __align__(16) short As[3][128 * 32];
  __shared__ __align__(16) short Bs[3][128 * 32];
  // bijective XCD swizzle: nwg = 24*72 = 1728, 216 contiguous work items/XCD
  int wg = blockIdx.x + 24 * blockIdx.y;
  int wl = (wg & 7) * 216 + (wg >> 3);
  int bx = wl % 24;           // n-tile
  int by = wl / 24;           // m-tile (9 consecutive per XCD share streaming A)
  if (by >= meta[0]) return;
  int tv = tile1[by];
  int e = tv >> 20;
  int m_base = tv & 0xFFFFF;
  int off_e = offs[e];
  int n_e = offs[e + 1] - off_e;
  int n0 = bx * 128;
  const short* A = (const short*)Xg + (size_t)(off_e + m_base) * DD;
  const short* B = (const short*)wfcT + (size_t)e * FF * DD + (size_t)n0 * DD;
  int tid = threadIdx.x;
  int lane = tid & 63, wid = tid >> 6;
  int l15 = lane & 15, q = lane >> 4;
  int wm = wid & 1, wn = wid >> 1;
  int fs0 = tid, fs1 = tid + 256;
  int m0 = fs0 >> 2, c0 = (fs0 & 3) ^ swz4(m0);
  int m1 = fs1 >> 2, c1 = (fs1 & 3) ^ swz4(m1);
  const short* gA0 = A + (size_t)m0 * DD + c0 * 8;
  const short* gA1 = A + (size_t)m1 * DD + c1 * 8;
  const short* gB0 = B + (size_t)m0 * DD + c0 * 8;
  const short* gB1 = B + (size_t)m1 * DD + c1 * 8;
  int aoff[4], boff[4];
#pragma unroll
  for (int mi = 0; mi < 4; ++mi) {
    int r = wm * 64 + mi * 16 + l15;
    aoff[mi] = (r * 4 + (q ^ swz4(r))) * 8;
  }
#pragma unroll
  for (int ni = 0; ni < 4; ++ni) {
    int r = wn * 64 + ni * 16 + l15;
    boff[ni] = (r * 4 + (q ^ swz4(r))) * 8;
  }
  f32x4 acc[4][4] = {};
  G_ISSUE(0)                       // k-step 0
  G_ISSUE(1)                       // k-step 1
  // NIT = DD/32 = 24 steps: 7 unrolled groups (k=0..20), one more issuing step
  // (k=21, stages step 23), then two tail steps.
  for (int g = 0; g < 7; ++g) {
    S_MAIN(0, 2)
    S_MAIN(1, 0)
    S_MAIN(2, 1)
  }
  S_MAIN(0, 2)
  S_TAIL(1, WVM4)
  S_TAIL(2, WVM0)
  float bias[4];
#pragma unroll
  for (int ni = 0; ni < 4; ++ni) bias[ni] = b_fc[e * FF + n0 + wn * 64 + ni * 16 + l15];
  __hip_bfloat16* Hp = H + (size_t)(off_e + m_base) * FF + n0;
#pragma unroll
  for (int mi = 0; mi < 4; ++mi) {
#pragma unroll
    for (int r = 0; r < 4; ++r) {
      int ml = wm * 64 + mi * 16 + q * 4 + r;
      if (m_base + ml < n_e) {
#pragma unroll
        for (int ni = 0; ni < 4; ++ni) {
          int nl = wn * 64 + ni * 16 + l15;
          float v = acc[mi][ni][r] + bias[ni];
          Hp[(size_t)ml * FF + nl] = __float2bfloat16(gelu_f(v));
        }
      }
    }
  }
}

// GEMM2: out[tok] += w(slot)*(H[slot] @ wprojT + b_proj); 128x128 tile, BK=32,
// split-K x2 (bias only on kz==0), 3-stage ring depth-2, ONE barrier per step,
// XCD swizzle. Fused combine via fp32 atomics.
__global__ __launch_bounds__(256) void gemm2_kernel(const __hip_bfloat16* __restrict__ H,
    const __hip_bfloat16* __restrict__ wprojT, const float* __restrict__ b_proj,
    const float* __restrict__ slotW, const int* __restrict__ slotTok,
    float* __restrict__ out, const int* __restrict__ offs,
    const int* __restrict__ tile1, const int* __restrict__ meta) {
  __shared__ __align__(16) short As[3][128 * 32];
  __shared__ __align__(16) short Bs[3][128 * 32];
  // bijective XCD swizzle: nwg = 6*72*2 = 864, 108 contiguous work items/XCD
  int wg = blockIdx.x + 6 * blockIdx.y + 432 * blockIdx.z;
  int wl = (wg & 7) * 108 + (wg >> 3);
  int bx = wl % 6;
  int rest = wl / 6;
  int by = rest % 72;
  int kz = wl / 432;               // split-K half: 0 or 1
  if (by >= meta[0]) return;
  int tv = tile1[by];
  int e = tv >> 20;
  int m_base = tv & 0xFFFFF;
  int off_e = offs[e];
  int n_e = offs[e + 1] - off_e;
  int n0 = bx * 128;
  const short* A = (const short*)H + (size_t)(off_e + m_base) * FF + kz * (FF / 2);
  const short* B = (const short*)wprojT + (size_t)e * DD * FF + (size_t)n0 * FF + kz * (FF / 2);
  int tid = threadIdx.x;
  int lane = tid & 63, wid = tid >> 6;
  int l15 = lane & 15, q = lane >> 4;
  int wm = wid & 1, wn = wid >> 1;
  int fs0 = tid, fs1 = tid + 256;
  int m0 = fs0 >> 2, c0 = (fs0 & 3) ^ swz4(m0);
  int m1 = fs1 >> 2, c1 = (fs1 & 3) ^ swz4(m1);
  const short* gA0 = A + (size_t)m0 * FF + c0 * 8;
  const short* gA1 = A + (size_t)m1 * FF + c1 * 8;
  const short* gB0 = B + (size_t)m0 * FF + c0 * 8;
  const short* gB1 = B + (size_t)m1 * FF + c1 * 8;
  int aoff[4], boff[4];
#pragma unroll
  for (int mi = 0; mi < 4; ++mi) {
    int r = wm * 64 + mi * 16 + l15;
    aoff[mi] = (r * 4 + (q ^ swz4(r))) * 8;
  }
#pragma unroll
  for (int ni = 0; ni < 4; ++ni) {
    int r = wn * 64 + ni * 16 + l15;
    boff[ni] = (r * 4 + (q ^ swz4(r))) * 8;
  }
  f32x4 acc[4][4] = {};
  G_ISSUE(0)
  G_ISSUE(1)
  // NIT = (FF/2)/32 = 48 steps: 15 groups (k=0..44), one issuing step (k=45,
  // stages step 47), two tail steps.
  for (int g = 0; g < 15; ++g) {
    S_MAIN(0, 2)
    S_MAIN(1, 0)
    S_MAIN(2, 1)
  }
  S_MAIN(0, 2)
  S_TAIL(1, WVM4)
  S_TAIL(2, WVM0)
  float bias[4];
#pragma unroll
  for (int ni = 0; ni < 4; ++ni)
    bias[ni] = (kz == 0) ? b_proj[e * DD + n0 + wn * 64 + ni * 16 + l15] : 0.f;
#pragma unroll
  for (int mi = 0; mi < 4; ++mi) {
#pragma unroll
    for (int r = 0; r < 4; ++r) {
      int ml = wm * 64 + mi * 16 + q * 4 + r;
      if (m_base + ml < n_e) {
        int slot = off_e + m_base + ml;
        float w = slotW[slot];
        int tok = slotTok[slot];
        float* op = out + (size_t)tok * DD + n0 + wn * 64;
#pragma unroll
        for (int ni = 0; ni < 4; ++ni)
          atomicAdd(&op[ni * 16 + l15], w * (acc[mi][ni][r] + bias[ni]));
      }
    }
  }
}

extern "C" void kernel_launch(void* const* d_in, const int* in_sizes, int n_in,
                              void* d_out, int out_size, void* d_ws, size_t ws_size,
                              hipStream_t stream) {
  const float* x        = (const float*)d_in[0];
  const float* router_w = (const float*)d_in[1];
  const float* w_fc     = (const float*)d_in[2];
  const float* b_fc     = (const float*)d_in[3];
  const float* w_proj   = (const float*)d_in[4];
  const float* b_proj   = (const float*)d_in[5];
  float* out = (float*)d_out;

  char* p = (char*)d_ws;
  auto alloc = [&](size_t bytes) {
    char* r = p;
    p += (bytes + 255) & ~(size_t)255;
    return r;
  };
  __hip_bfloat16* wfcT   = (__hip_bfloat16*)alloc((size_t)EE * FF * DD * 2);  // [E][F][D]
  __hip_bfloat16* wprojT = (__hip_bfloat16*)alloc((size_t)EE * DD * FF * 2);  // [E][D][F]
  __hip_bfloat16* Xg     = (__hip_bfloat16*)alloc((size_t)NSLOT_PAD * DD * 2);
  __hip_bfloat16* H      = (__hip_bfloat16*)alloc((size_t)NSLOT_PAD * FF * 2);
  int*   tokE    = (int*)alloc(TT * 2 * 4);
  float* tokW    = (float*)alloc(TT * 2 * 4);
  int*   slotIdx = (int*)alloc(TT * 2 * 4);
  float* slotW   = (float*)alloc(NSLOT_PAD * 4);
  int*   slotTok = (int*)alloc(NSLOT_PAD * 4);
  int*   blkCnt  = (int*)alloc(256 * EE * 4);
  int*   blkBase = (int*)alloc(256 * EE * 4);
  int*   tile1   = (int*)alloc(128 * 4);
  int*   tile2   = (int*)alloc(256 * 4);
  int*   offs    = (int*)alloc(64);
  int*   meta    = (int*)alloc(64);

  hipMemsetAsync(out, 0, (size_t)out_size * 4, stream);
  router2_kernel<<<256, 256, 0, stream>>>(x, router_w, tokE, tokW, blkCnt);
  offsets2_kernel<<<1, 256, 0, stream>>>(blkCnt, offs, blkBase, tile1, tile2, meta);
  scatter_gather2_kernel<<<256, 256, 0, stream>>>(x, tokE, tokW, blkBase, slotIdx, slotW, slotTok, Xg);
  transpose_convert_kernel<<<dim3(1152, 1, EE), 256, 0, stream>>>(w_fc, wfcT, w_proj, wprojT);
  gemm1_kernel<<<dim3(24, 72), 256, 0, stream>>>(Xg, wfcT, b_fc, H, offs, tile1, meta);
  gemm2_kernel<<<dim3(6, 72, 2), 256, 0, stream>>>(H, wprojT, b_proj, slotW, slotTok, out, offs, tile1, meta);
}

// Round 5
// 353.596 us; speedup vs baseline: 1.1097x; 1.1097x over previous
//
#include <hip/hip_runtime.h>
#include <hip/hip_bf16.h>

#define TT 4096      // tokens (B*S)
#define DD 768       // model dim
#define FF 3072      // ffn dim
#define EE 8         // experts
#define NSLOT 8192   // 2*TT (top-2)
#define NSLOT_PAD 8320

// s_waitcnt imm encodings (gfx9): vmcnt[3:0]|expcnt<<4|lgkmcnt<<8|vmcnt[5:4]<<14
#define WVM0  0x0F70   // vmcnt(0), lgkmcnt(15) -- own prev-stage loads landed

typedef __attribute__((ext_vector_type(8))) short bf16x8;
typedef __attribute__((ext_vector_type(4))) float f32x4;
typedef const __attribute__((address_space(1))) void* gas1_t;
typedef __attribute__((address_space(3))) void* las3_t;

// ---------------- router2: 256 blocks x 16 tokens; rw in LDS; no global atomics ----
__global__ __launch_bounds__(256) void router2_kernel(const float* __restrict__ x,
    const float* __restrict__ rw, int* __restrict__ tokE, float* __restrict__ tokW,
    int* __restrict__ blkCnt) {
  __shared__ float rws[EE * 832];
  __shared__ int cnt_s[EE];
  int tid = threadIdx.x;
  if (tid < EE) cnt_s[tid] = 0;
#pragma unroll
  for (int k = 0; k < 6; ++k) {
    int c = tid + k * 256;            // 0..1535
    int e = c / 192, rem = c % 192;
    int s = rem / 12, i = rem % 12;
    float4 v = *(const float4*)&rw[e * DD + s * 48 + i * 4];
    *(float4*)&rws[e * 832 + s * 52 + i * 4] = v;
  }
  __syncthreads();
  int lane = tid & 63;
  int sl = lane & 15;                  // d-slice
  int t = blockIdx.x * 16 + (tid >> 6) * 4 + (lane >> 4);
  const float4* xp = (const float4*)(x + (size_t)t * DD + sl * 48);
  float acc[EE];
#pragma unroll
  for (int e = 0; e < EE; ++e) acc[e] = 0.f;
#pragma unroll
  for (int i = 0; i < 12; ++i) {
    float4 xv = xp[i];
#pragma unroll
    for (int e = 0; e < EE; ++e) {
      float4 rv = *(const float4*)&rws[e * 832 + sl * 52 + i * 4];
      acc[e] = fmaf(xv.x, rv.x, fmaf(xv.y, rv.y, fmaf(xv.z, rv.z, fmaf(xv.w, rv.w, acc[e]))));
    }
  }
#pragma unroll
  for (int off = 8; off > 0; off >>= 1) {
#pragma unroll
    for (int e = 0; e < EE; ++e) acc[e] += __shfl_xor(acc[e], off);
  }
  if (sl == 0) {
    float v0 = -1e30f; int e0 = 0;
#pragma unroll
    for (int e = 0; e < EE; ++e) { if (acc[e] > v0) { v0 = acc[e]; e0 = e; } }
    float v1 = -1e30f; int e1 = 0;
#pragma unroll
    for (int e = 0; e < EE; ++e) { if (e != e0 && acc[e] > v1) { v1 = acc[e]; e1 = e; } }
    float w1 = 1.f / (1.f + __expf(v0 - v1));
    float w0 = 1.f - w1;
    tokE[2 * t] = e0; tokE[2 * t + 1] = e1;
    tokW[2 * t] = w0; tokW[2 * t + 1] = w1;
    atomicAdd(&cnt_s[e0], 1);
    atomicAdd(&cnt_s[e1], 1);
  }
  __syncthreads();
  if (tid < EE) blkCnt[blockIdx.x * EE + tid] = cnt_s[tid];
}

// ---------------- offsets2: 256-wide scan of blkCnt; offsets, bases, tile tables ---
__global__ __launch_bounds__(256) void offsets2_kernel(const int* __restrict__ blkCnt,
    int* __restrict__ offs, int* __restrict__ blkBase,
    int* __restrict__ tile1, int* __restrict__ tile2, int* __restrict__ meta) {
  __shared__ int wsum[4][EE];
  int tid = threadIdx.x;
  int lane = tid & 63, w = tid >> 6;
  int c[EE], s[EE];
#pragma unroll
  for (int e = 0; e < EE; ++e) { c[e] = blkCnt[tid * EE + e]; s[e] = c[e]; }
#pragma unroll
  for (int off = 1; off < 64; off <<= 1) {
#pragma unroll
    for (int e = 0; e < EE; ++e) {
      int v = __shfl_up(s[e], off);
      if (lane >= off) s[e] += v;
    }
  }
  if (lane == 63) {
#pragma unroll
    for (int e = 0; e < EE; ++e) wsum[w][e] = s[e];
  }
  __syncthreads();
#pragma unroll
  for (int e = 0; e < EE; ++e) {
    int pre = 0;
    for (int w2 = 0; w2 < w; ++w2) pre += wsum[w2][e];
    s[e] += pre;
  }
  int tot[EE];
#pragma unroll
  for (int e = 0; e < EE; ++e) tot[e] = wsum[0][e] + wsum[1][e] + wsum[2][e] + wsum[3][e];
  int offl[EE + 1];
  offl[0] = 0;
#pragma unroll
  for (int e = 0; e < EE; ++e) offl[e + 1] = offl[e] + tot[e];
#pragma unroll
  for (int e = 0; e < EE; ++e) blkBase[tid * EE + e] = offl[e] + s[e] - c[e];
  if (tid == 0) {
    for (int e = 0; e <= EE; ++e) offs[e] = offl[e];
    int n1 = 0, n2 = 0;
    for (int e = 0; e < EE; ++e) { n1 += (tot[e] + 127) / 128; n2 += (tot[e] + 63) / 64; }
    meta[0] = n1; meta[1] = n2;
  }
  if (tid < EE) {
    int p1 = 0, p2 = 0;
    for (int e = 0; e < tid; ++e) { p1 += (tot[e] + 127) / 128; p2 += (tot[e] + 63) / 64; }
    for (int m = 0; m < tot[tid]; m += 128) tile1[p1++] = (tid << 20) | m;
    for (int m = 0; m < tot[tid]; m += 64)  tile2[p2++] = (tid << 20) | m;
  }
}

// ---------------- scatter_gather2: coalesced copy to both slots; records slot->tok --
__global__ __launch_bounds__(256) void scatter_gather2_kernel(const float* __restrict__ x,
    const int* __restrict__ tokE, const float* __restrict__ tokW,
    const int* __restrict__ blkBase, int* __restrict__ slotIdx, float* __restrict__ slotW,
    int* __restrict__ slotTok, __hip_bfloat16* __restrict__ Xg) {
  __shared__ int base_s[EE], lcur[EE];
  __shared__ int sl_s[16][2];
  int tid = threadIdx.x;
  int b = blockIdx.x;
  if (tid < EE) { base_s[tid] = blkBase[b * EE + tid]; lcur[tid] = 0; }
  __syncthreads();
  if (tid < 16) {
    int t = b * 16 + tid;
    int e0 = tokE[2 * t], e1 = tokE[2 * t + 1];
    int s0 = base_s[e0] + atomicAdd(&lcur[e0], 1);
    int s1 = base_s[e1] + atomicAdd(&lcur[e1], 1);
    slotIdx[2 * t] = s0; slotIdx[2 * t + 1] = s1;
    slotW[s0] = tokW[2 * t]; slotW[s1] = tokW[2 * t + 1];
    slotTok[s0] = t; slotTok[s1] = t;
    sl_s[tid][0] = s0; sl_s[tid][1] = s1;
  }
  __syncthreads();
  int k = tid >> 4, p = tid & 15;
  int t = b * 16 + k;
  int s0 = sl_s[k][0], s1 = sl_s[k][1];
  const float4* src = (const float4*)(x + (size_t)t * DD);
  ushort4* d0 = (ushort4*)(Xg + (size_t)s0 * DD);
  ushort4* d1 = (ushort4*)(Xg + (size_t)s1 * DD);
#pragma unroll
  for (int i = 0; i < 12; ++i) {
    int idx = i * 16 + p;               // lanes contiguous -> coalesced 256B/128B
    float4 v = src[idx];
    union { ushort4 u; __hip_bfloat16 h[4]; } cv;
    cv.h[0] = __float2bfloat16(v.x);
    cv.h[1] = __float2bfloat16(v.y);
    cv.h[2] = __float2bfloat16(v.z);
    cv.h[3] = __float2bfloat16(v.w);
    d0[idx] = cv.u;
    d1[idx] = cv.u;
  }
}

// fused transpose-convert for both weight tensors: [K][N] fp32 -> [N][K] bf16
__global__ void transpose_convert_kernel(const float* __restrict__ w_fc, __hip_bfloat16* __restrict__ wfcT,
                                         const float* __restrict__ w_proj, __hip_bfloat16* __restrict__ wprojT) {
  __shared__ float tile[64][65];
  int bx = blockIdx.x;
  const float* S; __hip_bfloat16* D; int K, N, n0, k0;
  if (bx < 576) { S = w_fc;   D = wfcT;   K = DD; N = FF; n0 = (bx % 48) * 64; k0 = (bx / 48) * 64; }
  else { bx -= 576; S = w_proj; D = wprojT; K = FF; N = DD; n0 = (bx % 12) * 64; k0 = (bx / 12) * 64; }
  S += (size_t)blockIdx.z * K * N;
  D += (size_t)blockIdx.z * K * N;
  int tid = threadIdx.x;
#pragma unroll
  for (int i = 0; i < 4; ++i) {
    int slot = i * 256 + tid;
    int r = slot >> 4, c4 = slot & 15;
    float4 v = *(const float4*)&S[(size_t)(k0 + r) * N + n0 + c4 * 4];
    tile[r][c4 * 4 + 0] = v.x; tile[r][c4 * 4 + 1] = v.y;
    tile[r][c4 * 4 + 2] = v.z; tile[r][c4 * 4 + 3] = v.w;
  }
  __syncthreads();
#pragma unroll
  for (int i = 0; i < 4; ++i) {
    int slot = i * 256 + tid;
    int n = slot >> 4, kc = slot & 15;
    union { ushort4 u; __hip_bfloat16 h[4]; } cv;
    cv.h[0] = __float2bfloat16(tile[kc * 4 + 0][n]);
    cv.h[1] = __float2bfloat16(tile[kc * 4 + 1][n]);
    cv.h[2] = __float2bfloat16(tile[kc * 4 + 2][n]);
    cv.h[3] = __float2bfloat16(tile[kc * 4 + 3][n]);
    *(ushort4*)&D[(size_t)(n0 + n) * K + k0 + kc * 4] = cv.u;
  }
}

// fast exact-gelu via A&S 7.1.26 erf (max abs err 1.5e-7)
__device__ __forceinline__ float gelu_f(float v) {
  float z = v * 0.70710678118654752f;
  float az = fabsf(z);
  float t = 1.0f / (1.0f + 0.3275911f * az);
  float poly = t * (0.254829592f + t * (-0.284496736f + t * (1.421413741f +
               t * (-1.453152027f + t * 1.061405429f))));
  float erf_abs = 1.0f - poly * __expf(-az * az);
  float erf = copysignf(erf_abs, z);
  return 0.5f * v * (1.0f + erf);
}

// --- BK=64 2-stage pipelined K-step, ONE barrier per step ---
// Rows are 128B = 8 x 16B chunks; chunk swizzle c^(r&7): 16 consecutive rows
// spread over all 8 chunk slots (2 lanes/slot on ds_read_b128 = free, m136).
// LDS dest stays linear (global_load_lds requirement); the SOURCE address is
// pre-permuted with the same involution (both-sides rule).
// Step k: s_waitcnt vmcnt(0) [own step-k loads landed -- issued a full step
// (~1.5k cyc) earlier so this is near-free], s_barrier [all waves' k loads in
// AND all waves' k-1 ds_reads retired], issue step k+1 into buf (k+1)&1 [just
// protected by the barrier], ds_read buf k + 32 MFMA.
#define G_ISSUE(NXT) \
  _Pragma("unroll") for (int i = 0; i < 4; ++i) { \
    __builtin_amdgcn_global_load_lds((gas1_t)gA[i], (las3_t)(&As[NXT][0] + fsd[i]), 16, 0, 0); \
    __builtin_amdgcn_global_load_lds((gas1_t)gB[i], (las3_t)(&Bs[NXT][0] + fsd[i]), 16, 0, 0); \
    gA[i] += 64; gB[i] += 64; }

#define G_COMP(CUR) \
  { const short* cA = &As[CUR][0]; const short* cB = &Bs[CUR][0]; \
    _Pragma("unroll") for (int s = 0; s < 2; ++s) { \
      bf16x8 af[4], bfr[4]; \
      _Pragma("unroll") for (int mi = 0; mi < 4; ++mi) af[mi] = *(const bf16x8*)(cA + aoff[mi][s]); \
      _Pragma("unroll") for (int ni = 0; ni < 4; ++ni) bfr[ni] = *(const bf16x8*)(cB + boff[ni][s]); \
      _Pragma("unroll") for (int mi = 0; mi < 4; ++mi) \
        _Pragma("unroll") for (int ni = 0; ni < 4; ++ni) \
          acc[mi][ni] = __builtin_amdgcn_mfma_f32_16x16x32_bf16(af[mi], bfr[ni], acc[mi][ni], 0, 0, 0); } }

#define S_MAIN(CUR, NXT) \
  __builtin_amdgcn_s_waitcnt(WVM0); \
  __builtin_amdgcn_s_barrier(); \
  G_ISSUE(NXT) \
  G_COMP(CUR)

#define S_LAST(CUR) \
  __builtin_amdgcn_s_waitcnt(WVM0); \
  __builtin_amdgcn_s_barrier(); \
  G_COMP(CUR)

// shared per-gemm setup: fragment LDS offsets + staging src/dst for BK=64
#define GEMM_SETUP(STRIDE) \
  int tid = threadIdx.x; \
  int lane = tid & 63, wid = tid >> 6; \
  int l15 = lane & 15, q = lane >> 4; \
  int wm = wid & 1, wn = wid >> 1; \
  int fsd[4]; \
  const short* gA[4]; \
  const short* gB[4]; \
  _Pragma("unroll") for (int i = 0; i < 4; ++i) { \
    int fs = tid + i * 256; \
    int m = fs >> 3, c = (fs & 7) ^ (m & 7); \
    fsd[i] = fs * 8; \
    gA[i] = A + (size_t)m * STRIDE + c * 8; \
    gB[i] = B + (size_t)m * STRIDE + c * 8; \
  } \
  int aoff[4][2], boff[4][2]; \
  _Pragma("unroll") for (int mi = 0; mi < 4; ++mi) { \
    int r = wm * 64 + mi * 16 + l15; \
    _Pragma("unroll") for (int s = 0; s < 2; ++s) \
      aoff[mi][s] = r * 64 + ((((s << 2) | q) ^ (r & 7)) * 8); \
  } \
  _Pragma("unroll") for (int ni = 0; ni < 4; ++ni) { \
    int r = wn * 64 + ni * 16 + l15; \
    _Pragma("unroll") for (int s = 0; s < 2; ++s) \
      boff[ni][s] = r * 64 + ((((s << 2) | q) ^ (r & 7)) * 8); \
  } \
  f32x4 acc[4][4] = {};

// GEMM1: H = gelu(Xg @ wfcT + b_fc); 128x128 tile, BK=64, 2-stage depth-1,
// one barrier/step, 32 MFMA/step/wave; XCD-swizzled block mapping.
__global__ __launch_bounds__(256) void gemm1_kernel(const __hip_bfloat16* __restrict__ Xg,
    const __hip_bfloat16* __restrict__ wfcT, const float* __restrict__ b_fc,
    __hip_bfloat16* __restrict__ H, const int* __restrict__ offs,
    const int* __restrict__ tile1, const int* __restrict__ meta) {
  __shared__ __align__(16) short As[2][128 * 64];
  __shared__ __align__(16) short Bs[2][128 * 64];
  // bijective XCD swizzle: nwg = 24*72 = 1728, 216 contiguous work items/XCD
  int wg = blockIdx.x + 24 * blockIdx.y;
  int wl = (wg & 7) * 216 + (wg >> 3);
  int bx = wl % 24;           // n-tile
  int by = wl / 24;           // m-tile
  if (by >= meta[0]) return;
  int tv = tile1[by];
  int e = tv >> 20;
  int m_base = tv & 0xFFFFF;
  int off_e = offs[e];
  int n_e = offs[e + 1] - off_e;
  int n0 = bx * 128;
  const short* A = (const short*)Xg + (size_t)(off_e + m_base) * DD;
  const short* B = (const short*)wfcT + (size_t)e * FF * DD + (size_t)n0 * DD;
  GEMM_SETUP(DD)
  G_ISSUE(0)                       // stage step 0
  // NIT = DD/64 = 12 steps: 5 pairs (0..9), step 10 (issues 11), tail 11.
  for (int g = 0; g < 5; ++g) {
    S_MAIN(0, 1)
    S_MAIN(1, 0)
  }
  S_MAIN(0, 1)
  S_LAST(1)
  float bias[4];
#pragma unroll
  for (int ni = 0; ni < 4; ++ni) bias[ni] = b_fc[e * FF + n0 + wn * 64 + ni * 16 + l15];
  __hip_bfloat16* Hp = H + (size_t)(off_e + m_base) * FF + n0;
#pragma unroll
  for (int mi = 0; mi < 4; ++mi) {
#pragma unroll
    for (int r = 0; r < 4; ++r) {
      int ml = wm * 64 + mi * 16 + q * 4 + r;
      if (m_base + ml < n_e) {
#pragma unroll
        for (int ni = 0; ni < 4; ++ni) {
          int nl = wn * 64 + ni * 16 + l15;
          float v = acc[mi][ni][r] + bias[ni];
          Hp[(size_t)ml * FF + nl] = __float2bfloat16(gelu_f(v));
        }
      }
    }
  }
}

// GEMM2: out[tok] += w(slot)*(H[slot] @ wprojT + b_proj); 128x128 tile, BK=64,
// full K=3072 (no split-K: 48 steps amortize prologue/epilogue, atomics halved),
// 2-stage depth-1, one barrier/step, XCD swizzle. Fused combine via fp32 atomics.
__global__ __launch_bounds__(256) void gemm2_kernel(const __hip_bfloat16* __restrict__ H,
    const __hip_bfloat16* __restrict__ wprojT, const float* __restrict__ b_proj,
    const float* __restrict__ slotW, const int* __restrict__ slotTok,
    float* __restrict__ out, const int* __restrict__ offs,
    const int* __restrict__ tile1, const int* __restrict__ meta) {
  __shared__ __align__(16) short As[2][128 * 64];
  __shared__ __align__(16) short Bs[2][128 * 64];
  // bijective XCD swizzle: nwg = 6*72 = 432, 54 contiguous work items/XCD
  int wg = blockIdx.x + 6 * blockIdx.y;
  int wl = (wg & 7) * 54 + (wg >> 3);
  int bx = wl % 6;
  int by = wl / 6;
  if (by >= meta[0]) return;
  int tv = tile1[by];
  int e = tv >> 20;
  int m_base = tv & 0xFFFFF;
  int off_e = offs[e];
  int n_e = offs[e + 1] - off_e;
  int n0 = bx * 128;
  const short* A = (const short*)H + (size_t)(off_e + m_base) * FF;
  const short* B = (const short*)wprojT + (size_t)e * DD * FF + (size_t)n0 * FF;
  GEMM_SETUP(FF)
  G_ISSUE(0)                       // stage step 0
  // NIT = FF/64 = 48 steps: 23 pairs (0..45), step 46 (issues 47), tail 47.
  for (int g = 0; g < 23; ++g) {
    S_MAIN(0, 1)
    S_MAIN(1, 0)
  }
  S_MAIN(0, 1)
  S_LAST(1)
  float bias[4];
#pragma unroll
  for (int ni = 0; ni < 4; ++ni)
    bias[ni] = b_proj[e * DD + n0 + wn * 64 + ni * 16 + l15];
#pragma unroll
  for (int mi = 0; mi < 4; ++mi) {
#pragma unroll
    for (int r = 0; r < 4; ++r) {
      int ml = wm * 64 + mi * 16 + q * 4 + r;
      if (m_base + ml < n_e) {
        int slot = off_e + m_base + ml;
        float w = slotW[slot];
        int tok = slotTok[slot];
        float* op = out + (size_t)tok * DD + n0 + wn * 64;
#pragma unroll
        for (int ni = 0; ni < 4; ++ni)
          atomicAdd(&op[ni * 16 + l15], w * (acc[mi][ni][r] + bias[ni]));
      }
    }
  }
}

extern "C" void kernel_launch(void* const* d_in, const int* in_sizes, int n_in,
                              void* d_out, int out_size, void* d_ws, size_t ws_size,
                              hipStream_t stream) {
  const float* x        = (const float*)d_in[0];
  const float* router_w = (const float*)d_in[1];
  const float* w_fc     = (const float*)d_in[2];
  const float* b_fc     = (const float*)d_in[3];
  const float* w_proj   = (const float*)d_in[4];
  const float* b_proj   = (const float*)d_in[5];
  float* out = (float*)d_out;

  char* p = (char*)d_ws;
  auto alloc = [&](size_t bytes) {
    char* r = p;
    p += (bytes + 255) & ~(size_t)255;
    return r;
  };
  __hip_bfloat16* wfcT   = (__hip_bfloat16*)alloc((size_t)EE * FF * DD * 2);  // [E][F][D]
  __hip_bfloat16* wprojT = (__hip_bfloat16*)alloc((size_t)EE * DD * FF * 2);  // [E][D][F]
  __hip_bfloat16* Xg     = (__hip_bfloat16*)alloc((size_t)NSLOT_PAD * DD * 2);
  __hip_bfloat16* H      = (__hip_bfloat16*)alloc((size_t)NSLOT_PAD * FF * 2);
  int*   tokE    = (int*)alloc(TT * 2 * 4);
  float* tokW    = (float*)alloc(TT * 2 * 4);
  int*   slotIdx = (int*)alloc(TT * 2 * 4);
  float* slotW   = (float*)alloc(NSLOT_PAD * 4);
  int*   slotTok = (int*)alloc(NSLOT_PAD * 4);
  int*   blkCnt  = (int*)alloc(256 * EE * 4);
  int*   blkBase = (int*)alloc(256 * EE * 4);
  int*   tile1   = (int*)alloc(128 * 4);
  int*   tile2   = (int*)alloc(256 * 4);
  int*   offs    = (int*)alloc(64);
  int*   meta    = (int*)alloc(64);

  hipMemsetAsync(out, 0, (size_t)out_size * 4, stream);
  router2_kernel<<<256, 256, 0, stream>>>(x, router_w, tokE, tokW, blkCnt);
  offsets2_kernel<<<1, 256, 0, stream>>>(blkCnt, offs, blkBase, tile1, tile2, meta);
  scatter_gather2_kernel<<<256, 256, 0, stream>>>(x, tokE, tokW, blkBase, slotIdx, slotW, slotTok, Xg);
  transpose_convert_kernel<<<dim3(1152, 1, EE), 256, 0, stream>>>(w_fc, wfcT, w_proj, wprojT);
  gemm1_kernel<<<dim3(24, 72), 256, 0, stream>>>(Xg, wfcT, b_fc, H, offs, tile1, meta);
  gemm2_kernel<<<dim3(6, 72), 256, 0, stream>>>(H, wprojT, b_proj, slotW, slotTok, out, offs, tile1, meta);
}

// Round 6
// 340.835 us; speedup vs baseline: 1.1513x; 1.0374x over previous
//
#include <hip/hip_runtime.h>
#include <hip/hip_bf16.h>

#define TT 4096      // tokens (B*S)
#define DD 768       // model dim
#define FF 3072      // ffn dim
#define EE 8         // experts
#define NSLOT 8192   // 2*TT (top-2)
#define NSLOT_PAD 8448  // padded to 256-tile granularity (gemm1 stages 256 rows)

// s_waitcnt imm encodings (gfx9): vmcnt[3:0]|expcnt<<4|lgkmcnt<<8|vmcnt[5:4]<<14
#define WVM0  0x0F70   // vmcnt(0), lgkmcnt(15) -- own prev-stage loads landed

typedef __attribute__((ext_vector_type(8))) short bf16x8;
typedef __attribute__((ext_vector_type(4))) float f32x4;
typedef const __attribute__((address_space(1))) void* gas1_t;
typedef __attribute__((address_space(3))) void* las3_t;

// ---------------- router2: 256 blocks x 16 tokens; rw in LDS; no global atomics ----
__global__ __launch_bounds__(256) void router2_kernel(const float* __restrict__ x,
    const float* __restrict__ rw, int* __restrict__ tokE, float* __restrict__ tokW,
    int* __restrict__ blkCnt) {
  __shared__ float rws[EE * 832];
  __shared__ int cnt_s[EE];
  int tid = threadIdx.x;
  if (tid < EE) cnt_s[tid] = 0;
#pragma unroll
  for (int k = 0; k < 6; ++k) {
    int c = tid + k * 256;            // 0..1535
    int e = c / 192, rem = c % 192;
    int s = rem / 12, i = rem % 12;
    float4 v = *(const float4*)&rw[e * DD + s * 48 + i * 4];
    *(float4*)&rws[e * 832 + s * 52 + i * 4] = v;
  }
  __syncthreads();
  int lane = tid & 63;
  int sl = lane & 15;                  // d-slice
  int t = blockIdx.x * 16 + (tid >> 6) * 4 + (lane >> 4);
  const float4* xp = (const float4*)(x + (size_t)t * DD + sl * 48);
  float acc[EE];
#pragma unroll
  for (int e = 0; e < EE; ++e) acc[e] = 0.f;
#pragma unroll
  for (int i = 0; i < 12; ++i) {
    float4 xv = xp[i];
#pragma unroll
    for (int e = 0; e < EE; ++e) {
      float4 rv = *(const float4*)&rws[e * 832 + sl * 52 + i * 4];
      acc[e] = fmaf(xv.x, rv.x, fmaf(xv.y, rv.y, fmaf(xv.z, rv.z, fmaf(xv.w, rv.w, acc[e]))));
    }
  }
#pragma unroll
  for (int off = 8; off > 0; off >>= 1) {
#pragma unroll
    for (int e = 0; e < EE; ++e) acc[e] += __shfl_xor(acc[e], off);
  }
  if (sl == 0) {
    float v0 = -1e30f; int e0 = 0;
#pragma unroll
    for (int e = 0; e < EE; ++e) { if (acc[e] > v0) { v0 = acc[e]; e0 = e; } }
    float v1 = -1e30f; int e1 = 0;
#pragma unroll
    for (int e = 0; e < EE; ++e) { if (e != e0 && acc[e] > v1) { v1 = acc[e]; e1 = e; } }
    float w1 = 1.f / (1.f + __expf(v0 - v1));
    float w0 = 1.f - w1;
    tokE[2 * t] = e0; tokE[2 * t + 1] = e1;
    tokW[2 * t] = w0; tokW[2 * t + 1] = w1;
    atomicAdd(&cnt_s[e0], 1);
    atomicAdd(&cnt_s[e1], 1);
  }
  __syncthreads();
  if (tid < EE) blkCnt[blockIdx.x * EE + tid] = cnt_s[tid];
}

// ---------------- offsets2: 256-wide scan of blkCnt; offsets, bases, tile tables ---
// tile1: 128-granular m-tiles (gemm2); tile2: 256-granular m-tiles (gemm1).
__global__ __launch_bounds__(256) void offsets2_kernel(const int* __restrict__ blkCnt,
    int* __restrict__ offs, int* __restrict__ blkBase,
    int* __restrict__ tile1, int* __restrict__ tile2, int* __restrict__ meta) {
  __shared__ int wsum[4][EE];
  int tid = threadIdx.x;
  int lane = tid & 63, w = tid >> 6;
  int c[EE], s[EE];
#pragma unroll
  for (int e = 0; e < EE; ++e) { c[e] = blkCnt[tid * EE + e]; s[e] = c[e]; }
#pragma unroll
  for (int off = 1; off < 64; off <<= 1) {
#pragma unroll
    for (int e = 0; e < EE; ++e) {
      int v = __shfl_up(s[e], off);
      if (lane >= off) s[e] += v;
    }
  }
  if (lane == 63) {
#pragma unroll
    for (int e = 0; e < EE; ++e) wsum[w][e] = s[e];
  }
  __syncthreads();
#pragma unroll
  for (int e = 0; e < EE; ++e) {
    int pre = 0;
    for (int w2 = 0; w2 < w; ++w2) pre += wsum[w2][e];
    s[e] += pre;
  }
  int tot[EE];
#pragma unroll
  for (int e = 0; e < EE; ++e) tot[e] = wsum[0][e] + wsum[1][e] + wsum[2][e] + wsum[3][e];
  int offl[EE + 1];
  offl[0] = 0;
#pragma unroll
  for (int e = 0; e < EE; ++e) offl[e + 1] = offl[e] + tot[e];
#pragma unroll
  for (int e = 0; e < EE; ++e) blkBase[tid * EE + e] = offl[e] + s[e] - c[e];
  if (tid == 0) {
    for (int e = 0; e <= EE; ++e) offs[e] = offl[e];
    int n1 = 0, n2 = 0;
    for (int e = 0; e < EE; ++e) { n1 += (tot[e] + 127) / 128; n2 += (tot[e] + 255) / 256; }
    meta[0] = n1; meta[1] = n2;
  }
  if (tid < EE) {
    int p1 = 0, p2 = 0;
    for (int e = 0; e < tid; ++e) { p1 += (tot[e] + 127) / 128; p2 += (tot[e] + 255) / 256; }
    for (int m = 0; m < tot[tid]; m += 128) tile1[p1++] = (tid << 20) | m;
    for (int m = 0; m < tot[tid]; m += 256) tile2[p2++] = (tid << 20) | m;
  }
}

// ---------------- scatter_gather2: coalesced copy to both slots; records slot->tok --
__global__ __launch_bounds__(256) void scatter_gather2_kernel(const float* __restrict__ x,
    const int* __restrict__ tokE, const float* __restrict__ tokW,
    const int* __restrict__ blkBase, int* __restrict__ slotIdx, float* __restrict__ slotW,
    int* __restrict__ slotTok, __hip_bfloat16* __restrict__ Xg) {
  __shared__ int base_s[EE], lcur[EE];
  __shared__ int sl_s[16][2];
  int tid = threadIdx.x;
  int b = blockIdx.x;
  if (tid < EE) { base_s[tid] = blkBase[b * EE + tid]; lcur[tid] = 0; }
  __syncthreads();
  if (tid < 16) {
    int t = b * 16 + tid;
    int e0 = tokE[2 * t], e1 = tokE[2 * t + 1];
    int s0 = base_s[e0] + atomicAdd(&lcur[e0], 1);
    int s1 = base_s[e1] + atomicAdd(&lcur[e1], 1);
    slotIdx[2 * t] = s0; slotIdx[2 * t + 1] = s1;
    slotW[s0] = tokW[2 * t]; slotW[s1] = tokW[2 * t + 1];
    slotTok[s0] = t; slotTok[s1] = t;
    sl_s[tid][0] = s0; sl_s[tid][1] = s1;
  }
  __syncthreads();
  int k = tid >> 4, p = tid & 15;
  int t = b * 16 + k;
  int s0 = sl_s[k][0], s1 = sl_s[k][1];
  const float4* src = (const float4*)(x + (size_t)t * DD);
  ushort4* d0 = (ushort4*)(Xg + (size_t)s0 * DD);
  ushort4* d1 = (ushort4*)(Xg + (size_t)s1 * DD);
#pragma unroll
  for (int i = 0; i < 12; ++i) {
    int idx = i * 16 + p;               // lanes contiguous -> coalesced 256B/128B
    float4 v = src[idx];
    union { ushort4 u; __hip_bfloat16 h[4]; } cv;
    cv.h[0] = __float2bfloat16(v.x);
    cv.h[1] = __float2bfloat16(v.y);
    cv.h[2] = __float2bfloat16(v.z);
    cv.h[3] = __float2bfloat16(v.w);
    d0[idx] = cv.u;
    d1[idx] = cv.u;
  }
}

// fused transpose-convert for both weight tensors: [K][N] fp32 -> [N][K] bf16
__global__ void transpose_convert_kernel(const float* __restrict__ w_fc, __hip_bfloat16* __restrict__ wfcT,
                                         const float* __restrict__ w_proj, __hip_bfloat16* __restrict__ wprojT) {
  __shared__ float tile[64][65];
  int bx = blockIdx.x;
  const float* S; __hip_bfloat16* D; int K, N, n0, k0;
  if (bx < 576) { S = w_fc;   D = wfcT;   K = DD; N = FF; n0 = (bx % 48) * 64; k0 = (bx / 48) * 64; }
  else { bx -= 576; S = w_proj; D = wprojT; K = FF; N = DD; n0 = (bx % 12) * 64; k0 = (bx / 12) * 64; }
  S += (size_t)blockIdx.z * K * N;
  D += (size_t)blockIdx.z * K * N;
  int tid = threadIdx.x;
#pragma unroll
  for (int i = 0; i < 4; ++i) {
    int slot = i * 256 + tid;
    int r = slot >> 4, c4 = slot & 15;
    float4 v = *(const float4*)&S[(size_t)(k0 + r) * N + n0 + c4 * 4];
    tile[r][c4 * 4 + 0] = v.x; tile[r][c4 * 4 + 1] = v.y;
    tile[r][c4 * 4 + 2] = v.z; tile[r][c4 * 4 + 3] = v.w;
  }
  __syncthreads();
#pragma unroll
  for (int i = 0; i < 4; ++i) {
    int slot = i * 256 + tid;
    int n = slot >> 4, kc = slot & 15;
    union { ushort4 u; __hip_bfloat16 h[4]; } cv;
    cv.h[0] = __float2bfloat16(tile[kc * 4 + 0][n]);
    cv.h[1] = __float2bfloat16(tile[kc * 4 + 1][n]);
    cv.h[2] = __float2bfloat16(tile[kc * 4 + 2][n]);
    cv.h[3] = __float2bfloat16(tile[kc * 4 + 3][n]);
    *(ushort4*)&D[(size_t)(n0 + n) * K + k0 + kc * 4] = cv.u;
  }
}

// fast rcp (v_rcp_f32, ~1 ulp) -- avoids the exact-div expansion (~10 VALU instrs)
__device__ __forceinline__ float rcp_fast(float x) {
  float r; asm("v_rcp_f32 %0, %1" : "=v"(r) : "v"(x)); return r;
}

// fast exact-gelu via A&S 7.1.26 erf (max abs err ~1.5e-7 + 1ulp rcp)
__device__ __forceinline__ float gelu_f(float v) {
  float z = v * 0.70710678118654752f;
  float az = fabsf(z);
  float t = rcp_fast(1.0f + 0.3275911f * az);
  float poly = t * (0.254829592f + t * (-0.284496736f + t * (1.421413741f +
               t * (-1.453152027f + t * 1.061405429f))));
  float erf_abs = 1.0f - poly * __expf(-az * az);
  float erf = copysignf(erf_abs, z);
  return 0.5f * v * (1.0f + erf);
}

// ==================== gemm2 (unchanged from r5): 128x128, BK=64, 256 thr ==========
#define G_ISSUE(NXT) \
  _Pragma("unroll") for (int i = 0; i < 4; ++i) { \
    __builtin_amdgcn_global_load_lds((gas1_t)gA[i], (las3_t)(&As[NXT][0] + fsd[i]), 16, 0, 0); \
    __builtin_amdgcn_global_load_lds((gas1_t)gB[i], (las3_t)(&Bs[NXT][0] + fsd[i]), 16, 0, 0); \
    gA[i] += 64; gB[i] += 64; }

#define G_COMP(CUR) \
  { const short* cA = &As[CUR][0]; const short* cB = &Bs[CUR][0]; \
    _Pragma("unroll") for (int s = 0; s < 2; ++s) { \
      bf16x8 af[4], bfr[4]; \
      _Pragma("unroll") for (int mi = 0; mi < 4; ++mi) af[mi] = *(const bf16x8*)(cA + (aoff[mi] ^ (s * 32))); \
      _Pragma("unroll") for (int ni = 0; ni < 4; ++ni) bfr[ni] = *(const bf16x8*)(cB + (boff[ni] ^ (s * 32))); \
      _Pragma("unroll") for (int mi = 0; mi < 4; ++mi) \
        _Pragma("unroll") for (int ni = 0; ni < 4; ++ni) \
          acc[mi][ni] = __builtin_amdgcn_mfma_f32_16x16x32_bf16(af[mi], bfr[ni], acc[mi][ni], 0, 0, 0); } }

#define S_MAIN(CUR, NXT) \
  __builtin_amdgcn_s_waitcnt(WVM0); \
  __builtin_amdgcn_s_barrier(); \
  G_ISSUE(NXT) \
  G_COMP(CUR)

#define S_LAST(CUR) \
  __builtin_amdgcn_s_waitcnt(WVM0); \
  __builtin_amdgcn_s_barrier(); \
  G_COMP(CUR)

// GEMM2: out[tok] += w(slot)*(H[slot] @ wprojT + b_proj); 128x128 tile, BK=64,
// full K=3072, 2-stage depth-1, one barrier/step, XCD swizzle, fp32-atomic combine.
__global__ __launch_bounds__(256) void gemm2_kernel(const __hip_bfloat16* __restrict__ H,
    const __hip_bfloat16* __restrict__ wprojT, const float* __restrict__ b_proj,
    const float* __restrict__ slotW, const int* __restrict__ slotTok,
    float* __restrict__ out, const int* __restrict__ offs,
    const int* __restrict__ tile1, const int* __restrict__ meta) {
  __shared__ __align__(16) short As[2][128 * 64];
  __shared__ __align__(16) short Bs[2][128 * 64];
  // bijective XCD swizzle: nwg = 6*72 = 432, 54 contiguous work items/XCD
  int wg = blockIdx.x + 6 * blockIdx.y;
  int wl = (wg & 7) * 54 + (wg >> 3);
  int bx = wl % 6;
  int by = wl / 6;
  if (by >= meta[0]) return;
  int tv = tile1[by];
  int e = tv >> 20;
  int m_base = tv & 0xFFFFF;
  int off_e = offs[e];
  int n_e = offs[e + 1] - off_e;
  int n0 = bx * 128;
  const short* A = (const short*)H + (size_t)(off_e + m_base) * FF;
  const short* B = (const short*)wprojT + (size_t)e * DD * FF + (size_t)n0 * FF;
  int tid = threadIdx.x;
  int lane = tid & 63, wid = tid >> 6;
  int l15 = lane & 15, q = lane >> 4;
  int wm = wid & 1, wn = wid >> 1;
  int fsd[4];
  const short* gA[4];
  const short* gB[4];
#pragma unroll
  for (int i = 0; i < 4; ++i) {
    int fs = tid + i * 256;
    int m = fs >> 3, c = (fs & 7) ^ (m & 7);
    fsd[i] = fs * 8;
    gA[i] = A + (size_t)m * FF + c * 8;
    gB[i] = B + (size_t)m * FF + c * 8;
  }
  int aoff[4], boff[4];
#pragma unroll
  for (int mi = 0; mi < 4; ++mi) {
    int r = wm * 64 + mi * 16 + l15;
    aoff[mi] = r * 64 + ((q ^ (r & 7)) * 8);
  }
#pragma unroll
  for (int ni = 0; ni < 4; ++ni) {
    int r = wn * 64 + ni * 16 + l15;
    boff[ni] = r * 64 + ((q ^ (r & 7)) * 8);
  }
  f32x4 acc[4][4] = {};
  G_ISSUE(0)
  // NIT = FF/64 = 48 steps: 23 pairs (0..45), step 46 (issues 47), tail 47.
  for (int g = 0; g < 23; ++g) {
    S_MAIN(0, 1)
    S_MAIN(1, 0)
  }
  S_MAIN(0, 1)
  S_LAST(1)
  float bias[4];
#pragma unroll
  for (int ni = 0; ni < 4; ++ni)
    bias[ni] = b_proj[e * DD + n0 + wn * 64 + ni * 16 + l15];
#pragma unroll
  for (int mi = 0; mi < 4; ++mi) {
#pragma unroll
    for (int r = 0; r < 4; ++r) {
      int ml = wm * 64 + mi * 16 + q * 4 + r;
      if (m_base + ml < n_e) {
        int slot = off_e + m_base + ml;
        float w = slotW[slot];
        int tok = slotTok[slot];
        float* op = out + (size_t)tok * DD + n0 + wn * 64;
#pragma unroll
        for (int ni = 0; ni < 4; ++ni)
          atomicAdd(&op[ni * 16 + l15], w * (acc[mi][ni][r] + bias[ni]));
      }
    }
  }
}

// ==================== gemm1: 256x256 tile, 512 thr, 8 waves (2Mx4N), BK=64 =========
// Per-wave output 128x64 -> FLOP/LDS-byte 1.36x higher than 64x64 (LDS was the
// tightest pipe at ~70% busy in r5). 128 KB LDS -> 1 block/CU, 2 waves/SIMD
// (__launch_bounds__(512,2) caps VGPR at 256; acc = 128 VGPR). Same proven
// single-barrier depth-1 ring; compute phase (~2000 cyc) covers HBM latency.
#define G1_ISSUE(NXT) \
  _Pragma("unroll") for (int i = 0; i < 4; ++i) { \
    __builtin_amdgcn_global_load_lds((gas1_t)gA[i], (las3_t)(&As[NXT][0] + fsd[i]), 16, 0, 0); \
    __builtin_amdgcn_global_load_lds((gas1_t)gB[i], (las3_t)(&Bs[NXT][0] + fsd[i]), 16, 0, 0); \
    gA[i] += 64; gB[i] += 64; }

#define G1_COMP(CUR) \
  { const short* cA = &As[CUR][0]; const short* cB = &Bs[CUR][0]; \
    _Pragma("unroll") for (int s = 0; s < 2; ++s) { \
      bf16x8 af[8], bfr[4]; \
      _Pragma("unroll") for (int mi = 0; mi < 8; ++mi) af[mi] = *(const bf16x8*)(cA + (aoff[mi] ^ (s * 32))); \
      _Pragma("unroll") for (int ni = 0; ni < 4; ++ni) bfr[ni] = *(const bf16x8*)(cB + (boff[ni] ^ (s * 32))); \
      _Pragma("unroll") for (int mi = 0; mi < 8; ++mi) \
        _Pragma("unroll") for (int ni = 0; ni < 4; ++ni) \
          acc[mi][ni] = __builtin_amdgcn_mfma_f32_16x16x32_bf16(af[mi], bfr[ni], acc[mi][ni], 0, 0, 0); } }

#define S1_MAIN(CUR, NXT) \
  __builtin_amdgcn_s_waitcnt(WVM0); \
  __builtin_amdgcn_s_barrier(); \
  G1_ISSUE(NXT) \
  G1_COMP(CUR)

#define S1_LAST(CUR) \
  __builtin_amdgcn_s_waitcnt(WVM0); \
  __builtin_amdgcn_s_barrier(); \
  G1_COMP(CUR)

__global__ __launch_bounds__(512, 2) void gemm1_kernel(const __hip_bfloat16* __restrict__ Xg,
    const __hip_bfloat16* __restrict__ wfcT, const float* __restrict__ b_fc,
    __hip_bfloat16* __restrict__ H, const int* __restrict__ offs,
    const int* __restrict__ tile2, const int* __restrict__ meta) {
  __shared__ __align__(16) short As[2][256 * 64];   // 64 KB
  __shared__ __align__(16) short Bs[2][256 * 64];   // 64 KB
  // bijective XCD swizzle: nwg = 12*40 = 480, 60 contiguous work items/XCD
  int wg = blockIdx.x + 12 * blockIdx.y;
  int wl = (wg & 7) * 60 + (wg >> 3);
  int bx = wl % 12;           // n-tile (256 wide)
  int by = wl / 12;           // m-tile (256 rows)
  if (by >= meta[1]) return;
  int tv = tile2[by];
  int e = tv >> 20;
  int m_base = tv & 0xFFFFF;
  int off_e = offs[e];
  int n_e = offs[e + 1] - off_e;
  int n0 = bx * 256;
  const short* A = (const short*)Xg + (size_t)(off_e + m_base) * DD;
  const short* B = (const short*)wfcT + (size_t)e * FF * DD + (size_t)n0 * DD;
  int tid = threadIdx.x;
  int lane = tid & 63, wid = tid >> 6;
  int l15 = lane & 15, q = lane >> 4;
  int wm = wid & 1, wn = wid >> 1;          // 2 M-halves x 4 N-quarters
  int fsd[4];
  const short* gA[4];
  const short* gB[4];
#pragma unroll
  for (int i = 0; i < 4; ++i) {
    int fs = tid + i * 512;                 // 0..2047: 256 rows x 8 chunks
    int m = fs >> 3, c = (fs & 7) ^ (m & 7);
    fsd[i] = fs * 8;
    gA[i] = A + (size_t)m * DD + c * 8;
    gB[i] = B + (size_t)m * DD + c * 8;
  }
  int aoff[8], boff[4];
#pragma unroll
  for (int mi = 0; mi < 8; ++mi) {
    int r = wm * 128 + mi * 16 + l15;
    aoff[mi] = r * 64 + ((q ^ (r & 7)) * 8);
  }
#pragma unroll
  for (int ni = 0; ni < 4; ++ni) {
    int r = wn * 64 + ni * 16 + l15;
    boff[ni] = r * 64 + ((q ^ (r & 7)) * 8);
  }
  f32x4 acc[8][4] = {};
  G1_ISSUE(0)
  // NIT = DD/64 = 12 steps: 5 pairs (0..9), step 10 (issues 11), tail 11.
  for (int g = 0; g < 5; ++g) {
    S1_MAIN(0, 1)
    S1_MAIN(1, 0)
  }
  S1_MAIN(0, 1)
  S1_LAST(1)
  float bias[4];
#pragma unroll
  for (int ni = 0; ni < 4; ++ni) bias[ni] = b_fc[e * FF + n0 + wn * 64 + ni * 16 + l15];
  __hip_bfloat16* Hp = H + (size_t)(off_e + m_base) * FF + n0;
#pragma unroll
  for (int mi = 0; mi < 8; ++mi) {
#pragma unroll
    for (int r = 0; r < 4; ++r) {
      int ml = wm * 128 + mi * 16 + q * 4 + r;
      if (m_base + ml < n_e) {
#pragma unroll
        for (int ni = 0; ni < 4; ++ni) {
          int nl = wn * 64 + ni * 16 + l15;
          float v = acc[mi][ni][r] + bias[ni];
          Hp[(size_t)ml * FF + nl] = __float2bfloat16(gelu_f(v));
        }
      }
    }
  }
}

extern "C" void kernel_launch(void* const* d_in, const int* in_sizes, int n_in,
                              void* d_out, int out_size, void* d_ws, size_t ws_size,
                              hipStream_t stream) {
  const float* x        = (const float*)d_in[0];
  const float* router_w = (const float*)d_in[1];
  const float* w_fc     = (const float*)d_in[2];
  const float* b_fc     = (const float*)d_in[3];
  const float* w_proj   = (const float*)d_in[4];
  const float* b_proj   = (const float*)d_in[5];
  float* out = (float*)d_out;

  char* p = (char*)d_ws;
  auto alloc = [&](size_t bytes) {
    char* r = p;
    p += (bytes + 255) & ~(size_t)255;
    return r;
  };
  __hip_bfloat16* wfcT   = (__hip_bfloat16*)alloc((size_t)EE * FF * DD * 2);  // [E][F][D]
  __hip_bfloat16* wprojT = (__hip_bfloat16*)alloc((size_t)EE * DD * FF * 2);  // [E][D][F]
  __hip_bfloat16* Xg     = (__hip_bfloat16*)alloc((size_t)NSLOT_PAD * DD * 2);
  __hip_bfloat16* H      = (__hip_bfloat16*)alloc((size_t)NSLOT_PAD * FF * 2);
  int*   tokE    = (int*)alloc(TT * 2 * 4);
  float* tokW    = (float*)alloc(TT * 2 * 4);
  int*   slotIdx = (int*)alloc(TT * 2 * 4);
  float* slotW   = (float*)alloc(NSLOT_PAD * 4);
  int*   slotTok = (int*)alloc(NSLOT_PAD * 4);
  int*   blkCnt  = (int*)alloc(256 * EE * 4);
  int*   blkBase = (int*)alloc(256 * EE * 4);
  int*   tile1   = (int*)alloc(128 * 4);
  int*   tile2   = (int*)alloc(256 * 4);
  int*   offs    = (int*)alloc(64);
  int*   meta    = (int*)alloc(64);

  hipMemsetAsync(out, 0, (size_t)out_size * 4, stream);
  router2_kernel<<<256, 256, 0, stream>>>(x, router_w, tokE, tokW, blkCnt);
  offsets2_kernel<<<1, 256, 0, stream>>>(blkCnt, offs, blkBase, tile1, tile2, meta);
  scatter_gather2_kernel<<<256, 256, 0, stream>>>(x, tokE, tokW, blkBase, slotIdx, slotW, slotTok, Xg);
  transpose_convert_kernel<<<dim3(1152, 1, EE), 256, 0, stream>>>(w_fc, wfcT, w_proj, wprojT);
  gemm1_kernel<<<dim3(12, 40), 512, 0, stream>>>(Xg, wfcT, b_fc, H, offs, tile2, meta);
  gemm2_kernel<<<dim3(6, 72), 256, 0, stream>>>(H, wprojT, b_proj, slotW, slotTok, out, offs, tile1, meta);
}